// Round 6
// baseline (789.461 us; speedup 1.0000x reference)
//
#include <hip/hip_runtime.h>
#include <hip/hip_bf16.h>
#include <stdint.h>

// ---------------------------------------------------------------------------
// GQA per-token head-mixing attention, MI355X (gfx950)
// Round 6: round-4 GEMM geometry (128x128, BK=64, 4 waves, T2 swizzle) +
// explicit LDS double-buffer with counted vmcnt (T3 minimal pipeline):
//   stage(t+1) -> vmcnt(8) [waits only tile t's loads] -> s_barrier ->
//   ds_read+MFMA(t) -> s_barrier
// The stage->compute gap (~1000 cyc) hides the global->LDS latency that
// round 4 paid serially at every __syncthreads() vmcnt(0) drain.
// vmcnt counting is safe: the K-loop contains no other vmem ops (no spills
// at ~80 VGPR). WAR on buffers is ordered by the end-of-tile barrier.
// rope_attn and converts unchanged.
// ---------------------------------------------------------------------------

typedef __attribute__((ext_vector_type(8))) short short8;
typedef __attribute__((ext_vector_type(4))) float f32x4;
typedef uint16_t u16;

typedef __attribute__((address_space(1))) const void as1_const_void;
typedef __attribute__((address_space(3))) void as3_void;
#define GLD_LDS16(gp, lp)                                                     \
  __builtin_amdgcn_global_load_lds((as1_const_void*)(gp), (as3_void*)(lp),    \
                                   16, 0, 0)

#define BAR() asm volatile("s_barrier" ::: "memory")
#define VMCNT(n) asm volatile("s_waitcnt vmcnt(" #n ")" ::: "memory")

__device__ __forceinline__ float bf2f(u16 u) {
  uint32_t x = ((uint32_t)u) << 16;
  float f;
  __builtin_memcpy(&f, &x, 4);
  return f;
}
__device__ __forceinline__ u16 f2bf(float f) {
  uint32_t u;
  __builtin_memcpy(&u, &f, 4);
  u += 0x7fffu + ((u >> 16) & 1u);  // round-to-nearest-even
  return (u16)(u >> 16);
}

// ---------------- f32 -> bf16 convert, 4 elems/thread ----------------------
__global__ __launch_bounds__(256) void cvt_f32_to_bf16_v4(
    const float* __restrict__ s, u16* __restrict__ d, int n4) {
  int i = blockIdx.x * 256 + threadIdx.x;
  if (i >= n4) return;
  const float4 v = reinterpret_cast<const float4*>(s)[i];
  ushort4 o;
  o.x = f2bf(v.x);
  o.y = f2bf(v.y);
  o.z = f2bf(v.z);
  o.w = f2bf(v.w);
  reinterpret_cast<ushort4*>(d)[i] = o;
}

// ---------------- C = A @ B^T : A (MxK) bf16, B (NxK) bf16 -----------------
// 128x128 tile, BK=64, 4 waves (2x2, each 64x64), 16x16x32 bf16 MFMA.
// LDS tiles [128][64] u16, XOR-swizzled: phys = logical ^ ((row&7)<<4),
// staged via linear-dest global_load_lds + inverse-swizzled global source.
// Double-buffered; counted vmcnt(8) per tile (8 = gload_lds per thread/tile).
template <int OUT_F32>
__global__ __launch_bounds__(256, 2) void gemm_bt(
    const u16* __restrict__ A, const u16* __restrict__ B,
    void* __restrict__ Cout, int M, int N, int K) {
  __shared__ u16 sA[2][128 * 64];
  __shared__ u16 sB[2][128 * 64];
  const int tid = threadIdx.x;
  const int lane = tid & 63;
  const int wid = tid >> 6;
  const int m0 = blockIdx.y * 128;
  const int n0 = blockIdx.x * 128;
  const int wr = wid >> 1, wc = wid & 1;
  const int lr = lane & 15;
  const int kq = lane >> 4;  // 0..3

  f32x4 acc[4][4];
#pragma unroll
  for (int i = 0; i < 4; ++i)
#pragma unroll
    for (int j = 0; j < 4; ++j) acc[i][j] = {0.f, 0.f, 0.f, 0.f};

  const int nK = K >> 6;  // K / 64, >= 2

  // 8 gload_lds per thread per call (4 A + 4 B, interleaved).
  auto stage = [&](int buf, int kt) {
    const u16* Ag = A + (size_t)m0 * K + (size_t)kt * 64;
    const u16* Bg = B + (size_t)n0 * K + (size_t)kt * 64;
#pragma unroll
    for (int it = 0; it < 4; ++it) {
      const int o = it * 4096 + tid * 16;          // dest byte in tile
      const int row = o >> 7;                      // 128 B per row
      const int lch = ((o >> 4) & 7) ^ (row & 7);  // inv-swizzled src chunk
      GLD_LDS16(Ag + (size_t)row * K + lch * 8,
                (char*)sA[buf] + it * 4096 + wid * 1024);
      GLD_LDS16(Bg + (size_t)row * K + lch * 8,
                (char*)sB[buf] + it * 4096 + wid * 1024);
    }
  };

  stage(0, 0);  // prologue: tile 0 in flight

  int cur = 0;
  for (int kt = 0; kt < nK; ++kt, cur ^= 1) {
    if (kt + 1 < nK) {
      stage(cur ^ 1, kt + 1);  // issue next tile first (+8 vmem)
      VMCNT(8);                // wait ONLY tile kt's 8 loads
    } else {
      VMCNT(0);                // last tile: drain
    }
    BAR();  // all threads' tile-kt data visible; no vmcnt(0) drain here

    const u16* sAc = sA[cur];
    const u16* sBc = sB[cur];
#pragma unroll
    for (int kk = 0; kk < 2; ++kk) {
      short8 af[4], bfr[4];
#pragma unroll
      for (int f = 0; f < 4; ++f) {
        const int ra = wr * 64 + f * 16 + lr;
        const uint32_t La = (uint32_t)(ra * 128 + kk * 64 + kq * 16);
        af[f] = *reinterpret_cast<const short8*>(
            (const char*)sAc + (La ^ (((uint32_t)ra & 7) << 4)));
        const int rb = wc * 64 + f * 16 + lr;
        const uint32_t Lb = (uint32_t)(rb * 128 + kk * 64 + kq * 16);
        bfr[f] = *reinterpret_cast<const short8*>(
            (const char*)sBc + (Lb ^ (((uint32_t)rb & 7) << 4)));
      }
#pragma unroll
      for (int i = 0; i < 4; ++i)
#pragma unroll
        for (int j = 0; j < 4; ++j)
          acc[i][j] = __builtin_amdgcn_mfma_f32_16x16x32_bf16(
              af[i], bfr[j], acc[i][j], 0, 0, 0);
    }
    BAR();  // all reads of buf[cur] retired before iter kt+1 overwrites it
  }

  // Epilogue. C/D layout: col = lane&15, row = (lane>>4)*4 + e  [m89/m91].
  const int rbase = m0 + wr * 64 + (kq << 2);
  const int cbase = n0 + wc * 64 + lr;
  if (OUT_F32) {
    float* C = (float*)Cout;
#pragma unroll
    for (int i = 0; i < 4; ++i)
#pragma unroll
      for (int j = 0; j < 4; ++j)
#pragma unroll
        for (int e = 0; e < 4; ++e)
          C[(size_t)(rbase + i * 16 + e) * N + (cbase + j * 16)] =
              acc[i][j][e];
  } else {
    u16* C = (u16*)Cout;
#pragma unroll
    for (int i = 0; i < 4; ++i)
#pragma unroll
      for (int j = 0; j < 4; ++j)
#pragma unroll
        for (int e = 0; e < 4; ++e)
          C[(size_t)(rbase + i * 16 + e) * N + (cbase + j * 16)] =
              f2bf(acc[i][j][e]);
  }
}

// ---------------- RoPE + head-mix attention, one block per token -----------
__global__ __launch_bounds__(256) void rope_attn(
    const u16* __restrict__ qkv, u16* __restrict__ attn, int S) {
  __shared__ float cosv[64], sinv[64];
  __shared__ float sq[16][132];  // +4 pad: kills 16-way bank conflict on dot
  __shared__ float sk[16][132];
  __shared__ float sp[16][16];
  const int token = blockIdx.x;
  const int s = token & (S - 1);  // S = 4096 (pow2); position in sequence
  const int tid = threadIdx.x;
  const u16* base = qkv + (size_t)token * 6144;

  if (tid < 64) {
    const float inv = powf(10000.0f, -(float)tid * (1.0f / 64.0f));
    float sv, cv;
    sincosf((float)s * inv, &sv, &cv);
    cosv[tid] = cv;
    sinv[tid] = sv;
  }
  __syncthreads();

#pragma unroll
  for (int p = 0; p < 8; ++p) {
    const int idx = p * 256 + tid;  // 0..2047
    const int mat = idx >> 10;      // 0 = q, 1 = k
    const int rem = idx & 1023;
    const int h = rem >> 6;
    const int i = rem & 63;
    const u16* src = base + mat * 2048 + h * 128 + 2 * i;
    const float x1 = bf2f(src[0]);
    const float x2 = bf2f(src[1]);
    const float c = cosv[i], sn = sinv[i];
    float* dst = mat ? sk[h] : sq[h];
    dst[2 * i] = x1 * c - x2 * sn;
    dst[2 * i + 1] = x1 * sn + x2 * c;
  }
  __syncthreads();

  {
    const int h = tid >> 4;
    const int t = tid & 15;
    const int hp = ((h & 3) << 2) | (h >> 2);  // original head feeding new h
    float sc = 0.f;
#pragma unroll
    for (int d = 0; d < 128; ++d) sc += sq[hp][d] * sk[t][d];
    sc *= 0.08838834764831845f;  // 1/sqrt(128)
    float mx = sc;
#pragma unroll
    for (int o = 8; o; o >>= 1) mx = fmaxf(mx, __shfl_xor(mx, o, 16));
    const float e = __expf(sc - mx);
    float sum = e;
#pragma unroll
    for (int o = 8; o; o >>= 1) sum += __shfl_xor(sum, o, 16);
    sp[h][t] = e / sum;
  }
  __syncthreads();

  {
    const int h = tid >> 4;
    const int d0 = (tid & 15) * 8;
    const u16* vb = base + 4096;
    float o[8] = {0.f, 0.f, 0.f, 0.f, 0.f, 0.f, 0.f, 0.f};
#pragma unroll
    for (int t = 0; t < 16; ++t) {
      const float pr = sp[h][t];
      const short8 vv = *reinterpret_cast<const short8*>(vb + t * 128 + d0);
#pragma unroll
      for (int e = 0; e < 8; ++e) o[e] += pr * bf2f((u16)vv[e]);
    }
    short8 ov;
#pragma unroll
    for (int e = 0; e < 8; ++e) ov[e] = (short)f2bf(o[e]);
    *reinterpret_cast<short8*>(attn + (size_t)token * 2048 + h * 128 + d0) =
        ov;
  }
}

// ---------------------------------------------------------------------------
extern "C" void kernel_launch(void* const* d_in, const int* in_sizes, int n_in,
                              void* d_out, int out_size, void* d_ws,
                              size_t ws_size, hipStream_t stream) {
  (void)in_sizes;
  (void)n_in;
  (void)out_size;
  (void)ws_size;
  const float* x = (const float*)d_in[0];
  const float* Wq = (const float*)d_in[1];
  const float* Wk = (const float*)d_in[2];
  const float* Wv = (const float*)d_in[3];
  const float* Wo = (const float*)d_in[4];
  float* out = (float*)d_out;

  const int B = 4, S = 4096, D = 2048;
  const int M = B * S;  // 16384

  char* ws = (char*)d_ws;
  u16* xb = (u16*)ws;                          // M*D bf16; reused as attn
  u16* wqkv = (u16*)(ws + (size_t)M * D * 2);  // 3*D*D bf16
  u16* wo = (u16*)((char*)wqkv + (size_t)3 * D * D * 2);
  u16* qkv = (u16*)((char*)wo + (size_t)D * D * 2);  // M*3D bf16

  // bf16 conversions
  cvt_f32_to_bf16_v4<<<(M * D / 4 + 255) / 256, 256, 0, stream>>>(x, xb,
                                                                  M * D / 4);
  const int w4 = D * D / 4;
  cvt_f32_to_bf16_v4<<<(w4 + 255) / 256, 256, 0, stream>>>(Wq, wqkv, w4);
  cvt_f32_to_bf16_v4<<<(w4 + 255) / 256, 256, 0, stream>>>(
      Wk, wqkv + (size_t)D * D, w4);
  cvt_f32_to_bf16_v4<<<(w4 + 255) / 256, 256, 0, stream>>>(
      Wv, wqkv + (size_t)2 * D * D, w4);
  cvt_f32_to_bf16_v4<<<(w4 + 255) / 256, 256, 0, stream>>>(Wo, wo, w4);

  // qkv = x @ [Wq;Wk;Wv]^T   (M x 3D, bf16 out)
  gemm_bt<0><<<dim3(3 * D / 128, M / 128), 256, 0, stream>>>(xb, wqkv, qkv, M,
                                                             3 * D, D);
  // RoPE + per-token head attention -> attn (reuses xb)
  rope_attn<<<M, 256, 0, stream>>>(qkv, xb, S);
  // out = attn @ Wo^T (f32 out)
  gemm_bt<1><<<dim3(D / 128, M / 128), 256, 0, stream>>>(xb, wo, out, M, D, D);
}

// Round 7
// 671.131 us; speedup vs baseline: 1.1763x; 1.1763x over previous
//
#include <hip/hip_runtime.h>
#include <hip/hip_bf16.h>
#include <stdint.h>

// ---------------------------------------------------------------------------
// GQA per-token head-mixing attention, MI355X (gfx950)
// Round 7: round-6 double-buffer + counted vmcnt, FIXED: fragment loads are
// inline-asm ds_read_b128 (opaque to the compiler's waitcnt pass, so no
// auto-inserted vmcnt(0) drain — the r6 regression mechanism). Counted
// lgkmcnt(8) pipelines kk0's MFMA under kk1's reads. r4 geometry (128x128,
// BK=64, 4 waves, T2 swizzle) otherwise unchanged. rope_attn/converts as r4.
// ---------------------------------------------------------------------------

typedef __attribute__((ext_vector_type(8))) short short8;
typedef __attribute__((ext_vector_type(4))) float f32x4;
typedef uint16_t u16;

typedef __attribute__((address_space(1))) const void as1_const_void;
typedef __attribute__((address_space(3))) void as3_void;
#define GLD_LDS16(gp, lp)                                                     \
  __builtin_amdgcn_global_load_lds((as1_const_void*)(gp), (as3_void*)(lp),    \
                                   16, 0, 0)

#define BAR() asm volatile("s_barrier" ::: "memory")
#define VMCNT(n) asm volatile("s_waitcnt vmcnt(" #n ")" ::: "memory")
#define LGKM(n)                                          \
  {                                                      \
    asm volatile("s_waitcnt lgkmcnt(" #n ")" ::: "memory"); \
    __builtin_amdgcn_sched_barrier(0);                   \
  }

__device__ __forceinline__ short8 ds_read_b128p(const char* p) {
  short8 r;
  const __attribute__((address_space(3))) char* lp =
      (const __attribute__((address_space(3))) char*)p;
  asm volatile("ds_read_b128 %0, %1" : "=v"(r) : "v"(lp));
  return r;
}

__device__ __forceinline__ float bf2f(u16 u) {
  uint32_t x = ((uint32_t)u) << 16;
  float f;
  __builtin_memcpy(&f, &x, 4);
  return f;
}
__device__ __forceinline__ u16 f2bf(float f) {
  uint32_t u;
  __builtin_memcpy(&u, &f, 4);
  u += 0x7fffu + ((u >> 16) & 1u);  // round-to-nearest-even
  return (u16)(u >> 16);
}

// ---------------- f32 -> bf16 convert, 4 elems/thread ----------------------
__global__ __launch_bounds__(256) void cvt_f32_to_bf16_v4(
    const float* __restrict__ s, u16* __restrict__ d, int n4) {
  int i = blockIdx.x * 256 + threadIdx.x;
  if (i >= n4) return;
  const float4 v = reinterpret_cast<const float4*>(s)[i];
  ushort4 o;
  o.x = f2bf(v.x);
  o.y = f2bf(v.y);
  o.z = f2bf(v.z);
  o.w = f2bf(v.w);
  reinterpret_cast<ushort4*>(d)[i] = o;
}

// ---------------- C = A @ B^T : A (MxK) bf16, B (NxK) bf16 -----------------
// 128x128 tile, BK=64, 4 waves (2x2, each 64x64), 16x16x32 bf16 MFMA.
// LDS [128][64] u16 tiles, XOR swizzle phys = logical ^ ((row&7)<<4);
// staged via linear-dest global_load_lds + inverse-swizzled global source.
// Double-buffered; per tile: stage(t+1) -> vmcnt(8) -> s_barrier ->
// 16 asm ds_reads -> lgkm(8)->MFMA(kk0) -> lgkm(0)->MFMA(kk1) -> s_barrier.
template <int OUT_F32>
__global__ __launch_bounds__(256, 2) void gemm_bt(
    const u16* __restrict__ A, const u16* __restrict__ B,
    void* __restrict__ Cout, int M, int N, int K) {
  __shared__ u16 sA[2][128 * 64];
  __shared__ u16 sB[2][128 * 64];
  const int tid = threadIdx.x;
  const int lane = tid & 63;
  const int wid = tid >> 6;
  const int m0 = blockIdx.y * 128;
  const int n0 = blockIdx.x * 128;
  const int wr = wid >> 1, wc = wid & 1;
  const int lr = lane & 15;
  const int kq = lane >> 4;  // 0..3

  f32x4 acc[4][4];
#pragma unroll
  for (int i = 0; i < 4; ++i)
#pragma unroll
    for (int j = 0; j < 4; ++j) acc[i][j] = {0.f, 0.f, 0.f, 0.f};

  const int nK = K >> 6;  // K / 64, >= 2

  // 8 gload_lds per thread per call (4 A + 4 B interleaved).
  auto stage = [&](int buf, int kt) {
    const u16* Ag = A + (size_t)m0 * K + (size_t)kt * 64;
    const u16* Bg = B + (size_t)n0 * K + (size_t)kt * 64;
#pragma unroll
    for (int it = 0; it < 4; ++it) {
      const int o = it * 4096 + tid * 16;          // dest byte in tile
      const int row = o >> 7;                      // 128 B per row
      const int lch = ((o >> 4) & 7) ^ (row & 7);  // inv-swizzled src chunk
      GLD_LDS16(Ag + (size_t)row * K + lch * 8,
                (char*)sA[buf] + it * 4096 + wid * 1024);
      GLD_LDS16(Bg + (size_t)row * K + lch * 8,
                (char*)sB[buf] + it * 4096 + wid * 1024);
    }
  };

  stage(0, 0);  // prologue: tile 0 in flight

  int cur = 0;
  for (int kt = 0; kt < nK; ++kt, cur ^= 1) {
    if (kt + 1 < nK) {
      stage(cur ^ 1, kt + 1);  // issue next tile first (+8 vmem)
      VMCNT(8);                // wait ONLY tile kt's 8 loads
    } else {
      VMCNT(0);                // last tile: drain
    }
    BAR();  // all waves' tile-kt data visible

    const char* sAc = (const char*)sA[cur];
    const char* sBc = (const char*)sB[cur];
    short8 af[2][4], bfr[2][4];
    // issue all 16 reads (kk0 then kk1), opaque to compiler waitcnt pass
#pragma unroll
    for (int kk = 0; kk < 2; ++kk)
#pragma unroll
      for (int f = 0; f < 4; ++f) {
        const int ra = wr * 64 + f * 16 + lr;
        const uint32_t La = (uint32_t)(ra * 128 + kk * 64 + kq * 16);
        af[kk][f] = ds_read_b128p(sAc + (La ^ (((uint32_t)ra & 7) << 4)));
        const int rb = wc * 64 + f * 16 + lr;
        const uint32_t Lb = (uint32_t)(rb * 128 + kk * 64 + kq * 16);
        bfr[kk][f] = ds_read_b128p(sBc + (Lb ^ (((uint32_t)rb & 7) << 4)));
      }
    LGKM(8);  // kk0's 8 reads done (in-order ds retirement)
    __builtin_amdgcn_s_setprio(1);
#pragma unroll
    for (int i = 0; i < 4; ++i)
#pragma unroll
      for (int j = 0; j < 4; ++j)
        acc[i][j] = __builtin_amdgcn_mfma_f32_16x16x32_bf16(
            af[0][i], bfr[0][j], acc[i][j], 0, 0, 0);
    __builtin_amdgcn_s_setprio(0);
    LGKM(0);  // kk1's reads done
    __builtin_amdgcn_s_setprio(1);
#pragma unroll
    for (int i = 0; i < 4; ++i)
#pragma unroll
      for (int j = 0; j < 4; ++j)
        acc[i][j] = __builtin_amdgcn_mfma_f32_16x16x32_bf16(
            af[1][i], bfr[1][j], acc[i][j], 0, 0, 0);
    __builtin_amdgcn_s_setprio(0);
    BAR();  // all reads of buf[cur] retired before iter kt+1 overwrites it
  }

  // Epilogue. C/D layout: col = lane&15, row = (lane>>4)*4 + e  [m89/m91].
  const int rbase = m0 + wr * 64 + (kq << 2);
  const int cbase = n0 + wc * 64 + lr;
  if (OUT_F32) {
    float* C = (float*)Cout;
#pragma unroll
    for (int i = 0; i < 4; ++i)
#pragma unroll
      for (int j = 0; j < 4; ++j)
#pragma unroll
        for (int e = 0; e < 4; ++e)
          C[(size_t)(rbase + i * 16 + e) * N + (cbase + j * 16)] =
              acc[i][j][e];
  } else {
    u16* C = (u16*)Cout;
#pragma unroll
    for (int i = 0; i < 4; ++i)
#pragma unroll
      for (int j = 0; j < 4; ++j)
#pragma unroll
        for (int e = 0; e < 4; ++e)
          C[(size_t)(rbase + i * 16 + e) * N + (cbase + j * 16)] =
              f2bf(acc[i][j][e]);
  }
}

// ---------------- RoPE + head-mix attention, one block per token -----------
__global__ __launch_bounds__(256) void rope_attn(
    const u16* __restrict__ qkv, u16* __restrict__ attn, int S) {
  __shared__ float cosv[64], sinv[64];
  __shared__ float sq[16][132];  // +4 pad: kills 16-way bank conflict on dot
  __shared__ float sk[16][132];
  __shared__ float sp[16][16];
  const int token = blockIdx.x;
  const int s = token & (S - 1);  // S = 4096 (pow2); position in sequence
  const int tid = threadIdx.x;
  const u16* base = qkv + (size_t)token * 6144;

  if (tid < 64) {
    const float inv = powf(10000.0f, -(float)tid * (1.0f / 64.0f));
    float sv, cv;
    sincosf((float)s * inv, &sv, &cv);
    cosv[tid] = cv;
    sinv[tid] = sv;
  }
  __syncthreads();

#pragma unroll
  for (int p = 0; p < 8; ++p) {
    const int idx = p * 256 + tid;  // 0..2047
    const int mat = idx >> 10;      // 0 = q, 1 = k
    const int rem = idx & 1023;
    const int h = rem >> 6;
    const int i = rem & 63;
    const u16* src = base + mat * 2048 + h * 128 + 2 * i;
    const float x1 = bf2f(src[0]);
    const float x2 = bf2f(src[1]);
    const float c = cosv[i], sn = sinv[i];
    float* dst = mat ? sk[h] : sq[h];
    dst[2 * i] = x1 * c - x2 * sn;
    dst[2 * i + 1] = x1 * sn + x2 * c;
  }
  __syncthreads();

  {
    const int h = tid >> 4;
    const int t = tid & 15;
    const int hp = ((h & 3) << 2) | (h >> 2);  // original head feeding new h
    float sc = 0.f;
#pragma unroll
    for (int d = 0; d < 128; ++d) sc += sq[hp][d] * sk[t][d];
    sc *= 0.08838834764831845f;  // 1/sqrt(128)
    float mx = sc;
#pragma unroll
    for (int o = 8; o; o >>= 1) mx = fmaxf(mx, __shfl_xor(mx, o, 16));
    const float e = __expf(sc - mx);
    float sum = e;
#pragma unroll
    for (int o = 8; o; o >>= 1) sum += __shfl_xor(sum, o, 16);
    sp[h][t] = e / sum;
  }
  __syncthreads();

  {
    const int h = tid >> 4;
    const int d0 = (tid & 15) * 8;
    const u16* vb = base + 4096;
    float o[8] = {0.f, 0.f, 0.f, 0.f, 0.f, 0.f, 0.f, 0.f};
#pragma unroll
    for (int t = 0; t < 16; ++t) {
      const float pr = sp[h][t];
      const short8 vv = *reinterpret_cast<const short8*>(vb + t * 128 + d0);
#pragma unroll
      for (int e = 0; e < 8; ++e) o[e] += pr * bf2f((u16)vv[e]);
    }
    short8 ov;
#pragma unroll
    for (int e = 0; e < 8; ++e) ov[e] = (short)f2bf(o[e]);
    *reinterpret_cast<short8*>(attn + (size_t)token * 2048 + h * 128 + d0) =
        ov;
  }
}

// ---------------------------------------------------------------------------
extern "C" void kernel_launch(void* const* d_in, const int* in_sizes, int n_in,
                              void* d_out, int out_size, void* d_ws,
                              size_t ws_size, hipStream_t stream) {
  (void)in_sizes;
  (void)n_in;
  (void)out_size;
  (void)ws_size;
  const float* x = (const float*)d_in[0];
  const float* Wq = (const float*)d_in[1];
  const float* Wk = (const float*)d_in[2];
  const float* Wv = (const float*)d_in[3];
  const float* Wo = (const float*)d_in[4];
  float* out = (float*)d_out;

  const int B = 4, S = 4096, D = 2048;
  const int M = B * S;  // 16384

  char* ws = (char*)d_ws;
  u16* xb = (u16*)ws;                          // M*D bf16; reused as attn
  u16* wqkv = (u16*)(ws + (size_t)M * D * 2);  // 3*D*D bf16
  u16* wo = (u16*)((char*)wqkv + (size_t)3 * D * D * 2);
  u16* qkv = (u16*)((char*)wo + (size_t)D * D * 2);  // M*3D bf16

  // bf16 conversions
  cvt_f32_to_bf16_v4<<<(M * D / 4 + 255) / 256, 256, 0, stream>>>(x, xb,
                                                                  M * D / 4);
  const int w4 = D * D / 4;
  cvt_f32_to_bf16_v4<<<(w4 + 255) / 256, 256, 0, stream>>>(Wq, wqkv, w4);
  cvt_f32_to_bf16_v4<<<(w4 + 255) / 256, 256, 0, stream>>>(
      Wk, wqkv + (size_t)D * D, w4);
  cvt_f32_to_bf16_v4<<<(w4 + 255) / 256, 256, 0, stream>>>(
      Wv, wqkv + (size_t)2 * D * D, w4);
  cvt_f32_to_bf16_v4<<<(w4 + 255) / 256, 256, 0, stream>>>(Wo, wo, w4);

  // qkv = x @ [Wq;Wk;Wv]^T   (M x 3D, bf16 out)
  gemm_bt<0><<<dim3(3 * D / 128, M / 128), 256, 0, stream>>>(xb, wqkv, qkv, M,
                                                             3 * D, D);
  // RoPE + per-token head attention -> attn (reuses xb)
  rope_attn<<<M, 256, 0, stream>>>(qkv, xb, S);
  // out = attn @ Wo^T (f32 out)
  gemm_bt<1><<<dim3(D / 128, M / 128), 256, 0, stream>>>(xb, wo, out, M, D, D);
}

// Round 8
// 651.150 us; speedup vs baseline: 1.2124x; 1.0307x over previous
//
#include <hip/hip_runtime.h>
#include <hip/hip_bf16.h>
#include <stdint.h>

// ---------------------------------------------------------------------------
// GQA per-token head-mixing attention, MI355X (gfx950)
// Round 8: GEMMs = round-4 exactly (best: 397us QKV, MfmaUtil 50.7, 0 confl).
// NEW rope_attn2: one WAVE per token (4 tokens/block):
//   - q,k loaded directly into MFMA fragment layout, RoPE in-register
//   - scores^T via 4x mfma_f32_16x16x32_bf16 (replaces 64K serial LDS MACs)
//   - softmax: in-lane + shfl_xor(16/32)
//   - PV: p->pld[t][h], v->vld[t][d] (pad 136), lane owns (h, 32 d's):
//     broadcast reads, 512 VALU FMA. All wave-private (no barriers).
// NEW cvt_w4: 4 weight matrices converted in one launch (contiguous dest).
// ---------------------------------------------------------------------------

typedef __attribute__((ext_vector_type(8))) short short8;
typedef __attribute__((ext_vector_type(4))) float f32x4;
typedef uint16_t u16;

typedef __attribute__((address_space(1))) const void as1_const_void;
typedef __attribute__((address_space(3))) void as3_void;
#define GLD_LDS16(gp, lp)                                                     \
  __builtin_amdgcn_global_load_lds((as1_const_void*)(gp), (as3_void*)(lp),    \
                                   16, 0, 0)

__device__ __forceinline__ float bf2f(u16 u) {
  uint32_t x = ((uint32_t)u) << 16;
  float f;
  __builtin_memcpy(&f, &x, 4);
  return f;
}
__device__ __forceinline__ u16 f2bf(float f) {
  uint32_t u;
  __builtin_memcpy(&u, &f, 4);
  u += 0x7fffu + ((u >> 16) & 1u);  // round-to-nearest-even
  return (u16)(u >> 16);
}

// ---------------- f32 -> bf16 convert, 4 elems/thread ----------------------
__global__ __launch_bounds__(256) void cvt_f32_to_bf16_v4(
    const float* __restrict__ s, u16* __restrict__ d, int n4) {
  int i = blockIdx.x * 256 + threadIdx.x;
  if (i >= n4) return;
  const float4 v = reinterpret_cast<const float4*>(s)[i];
  ushort4 o;
  o.x = f2bf(v.x);
  o.y = f2bf(v.y);
  o.z = f2bf(v.z);
  o.w = f2bf(v.w);
  reinterpret_cast<ushort4*>(d)[i] = o;
}

// ---- 4 weight matrices (each D*D f32) -> contiguous bf16 dest, one launch --
__global__ __launch_bounds__(256) void cvt_w4(
    const float* __restrict__ w0, const float* __restrict__ w1,
    const float* __restrict__ w2, const float* __restrict__ w3,
    u16* __restrict__ dst) {
  const int i = blockIdx.x * 256 + threadIdx.x;  // quad index, 4 * 2^20 total
  const int m = i >> 20;
  const int r = i & ((1 << 20) - 1);
  const float* src = (m == 0) ? w0 : (m == 1) ? w1 : (m == 2) ? w2 : w3;
  const float4 v = reinterpret_cast<const float4*>(src)[r];
  ushort4 o;
  o.x = f2bf(v.x);
  o.y = f2bf(v.y);
  o.z = f2bf(v.z);
  o.w = f2bf(v.w);
  reinterpret_cast<ushort4*>(dst)[i] = o;
}

// ---------------- C = A @ B^T (round-4 proven GEMM, unchanged) -------------
template <int OUT_F32>
__global__ __launch_bounds__(256, 2) void gemm_bt(
    const u16* __restrict__ A, const u16* __restrict__ B,
    void* __restrict__ Cout, int M, int N, int K) {
  __shared__ u16 sA[128 * 64];
  __shared__ u16 sB[128 * 64];
  const int tid = threadIdx.x;
  const int lane = tid & 63;
  const int wid = tid >> 6;
  const int m0 = blockIdx.y * 128;
  const int n0 = blockIdx.x * 128;
  const int wr = wid >> 1, wc = wid & 1;
  const int lr = lane & 15;
  const int kq = lane >> 4;  // 0..3

  f32x4 acc[4][4];
#pragma unroll
  for (int i = 0; i < 4; ++i)
#pragma unroll
    for (int j = 0; j < 4; ++j) acc[i][j] = {0.f, 0.f, 0.f, 0.f};

  const int nK = K >> 6;  // K / 64
  for (int kt = 0; kt < nK; ++kt) {
    const u16* Ag = A + (size_t)m0 * K + kt * 64;
    const u16* Bg = B + (size_t)n0 * K + kt * 64;
#pragma unroll
    for (int it = 0; it < 4; ++it) {
      const int o = it * 4096 + tid * 16;
      const int row = o >> 7;
      const int lch = ((o >> 4) & 7) ^ (row & 7);
      GLD_LDS16(Ag + (size_t)row * K + lch * 8,
                (char*)sA + it * 4096 + wid * 1024);
    }
#pragma unroll
    for (int it = 0; it < 4; ++it) {
      const int o = it * 4096 + tid * 16;
      const int row = o >> 7;
      const int lch = ((o >> 4) & 7) ^ (row & 7);
      GLD_LDS16(Bg + (size_t)row * K + lch * 8,
                (char*)sB + it * 4096 + wid * 1024);
    }
    __syncthreads();

#pragma unroll
    for (int kk = 0; kk < 2; ++kk) {
      short8 af[4], bfr[4];
#pragma unroll
      for (int f = 0; f < 4; ++f) {
        const int ra = wr * 64 + f * 16 + lr;
        const uint32_t La = (uint32_t)(ra * 128 + kk * 64 + kq * 16);
        af[f] = *reinterpret_cast<const short8*>(
            (const char*)sA + (La ^ (((uint32_t)ra & 7) << 4)));
        const int rb = wc * 64 + f * 16 + lr;
        const uint32_t Lb = (uint32_t)(rb * 128 + kk * 64 + kq * 16);
        bfr[f] = *reinterpret_cast<const short8*>(
            (const char*)sB + (Lb ^ (((uint32_t)rb & 7) << 4)));
      }
#pragma unroll
      for (int i = 0; i < 4; ++i)
#pragma unroll
        for (int j = 0; j < 4; ++j)
          acc[i][j] = __builtin_amdgcn_mfma_f32_16x16x32_bf16(
              af[i], bfr[j], acc[i][j], 0, 0, 0);
    }
    __syncthreads();
  }

  const int rbase = m0 + wr * 64 + (kq << 2);
  const int cbase = n0 + wc * 64 + lr;
  if (OUT_F32) {
    float* C = (float*)Cout;
#pragma unroll
    for (int i = 0; i < 4; ++i)
#pragma unroll
      for (int j = 0; j < 4; ++j)
#pragma unroll
        for (int e = 0; e < 4; ++e)
          C[(size_t)(rbase + i * 16 + e) * N + (cbase + j * 16)] =
              acc[i][j][e];
  } else {
    u16* C = (u16*)Cout;
#pragma unroll
    for (int i = 0; i < 4; ++i)
#pragma unroll
      for (int j = 0; j < 4; ++j)
#pragma unroll
        for (int e = 0; e < 4; ++e)
          C[(size_t)(rbase + i * 16 + e) * N + (cbase + j * 16)] =
              f2bf(acc[i][j][e]);
  }
}

// ---------------- RoPE + head-mix attention, one WAVE per token ------------
// Wave layout facts used (verified in this session's GEMM, m89/m91):
//   mfma_16x16x32 A/B-frag: lane holds row (lane&15), k = (lane>>4)*8+e
//   C/D: col = lane&15, row = (lane>>4)*4 + e
// scores^T = mfma(k_frag, q_frag): lane gets S^T[t=(l>>4)*4+e][h=l&15].
__global__ __launch_bounds__(256) void rope_attn2(
    const u16* __restrict__ qkv, u16* __restrict__ attn, int S) {
  __shared__ u16 vld[4][16][136];   // per-wave v rows, +8 pad (bank spread)
  __shared__ float pld[4][16][17];  // per-wave p[t][h], +1 pad
  const int tid = threadIdx.x;
  const int l = tid & 63;
  const int w = tid >> 6;
  const int token = blockIdx.x * 4 + w;
  const int pos = token & (S - 1);
  const u16* base = qkv + (size_t)token * 6144;

  // ---- v global loads issued early (hide under trig/scores) ----
  const int vt = l >> 2, vd0 = (l & 3) * 32;
  short8 vreg[4];
  {
    const u16* vsrc = base + 4096 + vt * 128 + vd0;
#pragma unroll
    for (int c = 0; c < 4; ++c)
      vreg[c] = *reinterpret_cast<const short8*>(vsrc + c * 8);
  }

  // ---- q/k frags + RoPE in-register ----
  // lane's k-chunk for mfma kk: d0 = kk*32 + (l>>4)*8 ; pairs i = d0/2 + j
  const int hq = (((l & 15) & 3) << 2) | ((l & 15) >> 2);  // q head permute
  const u16* qsrc = base + hq * 128;
  const u16* ksrc = base + 2048 + (l & 15) * 128;
  short8 aq[4], ak[4];
#pragma unroll
  for (int kk = 0; kk < 4; ++kk) {
    const int d0 = kk * 32 + ((l >> 4) << 3);
    const short8 qv = *reinterpret_cast<const short8*>(qsrc + d0);
    const short8 kv = *reinterpret_cast<const short8*>(ksrc + d0);
    short8 qo, ko;
#pragma unroll
    for (int j = 0; j < 4; ++j) {
      const int i = (d0 >> 1) + j;
      const float invf = __expf(-0.14391156831212787f * (float)i);
      float sv, cv;
      sincosf((float)pos * invf, &sv, &cv);
      const float q1 = bf2f((u16)qv[2 * j]), q2 = bf2f((u16)qv[2 * j + 1]);
      const float k1 = bf2f((u16)kv[2 * j]), k2 = bf2f((u16)kv[2 * j + 1]);
      qo[2 * j] = (short)f2bf(q1 * cv - q2 * sv);
      qo[2 * j + 1] = (short)f2bf(q1 * sv + q2 * cv);
      ko[2 * j] = (short)f2bf(k1 * cv - k2 * sv);
      ko[2 * j + 1] = (short)f2bf(k1 * sv + k2 * cv);
    }
    aq[kk] = qo;
    ak[kk] = ko;
  }

  // ---- scores^T via 4 MFMAs ----
  f32x4 accS = {0.f, 0.f, 0.f, 0.f};
#pragma unroll
  for (int kk = 0; kk < 4; ++kk)
    accS = __builtin_amdgcn_mfma_f32_16x16x32_bf16(ak[kk], aq[kk], accS, 0, 0,
                                                   0);

  // ---- softmax over t (fixed h = l&15): 4 in-lane + groups via xor16/32 ---
  float p[4];
  float mx = -3.4e38f;
#pragma unroll
  for (int e = 0; e < 4; ++e) {
    p[e] = accS[e] * 0.08838834764831845f;
    mx = fmaxf(mx, p[e]);
  }
  mx = fmaxf(mx, __shfl_xor(mx, 16));
  mx = fmaxf(mx, __shfl_xor(mx, 32));
  float sum = 0.f;
#pragma unroll
  for (int e = 0; e < 4; ++e) {
    p[e] = __expf(p[e] - mx);
    sum += p[e];
  }
  sum += __shfl_xor(sum, 16);
  sum += __shfl_xor(sum, 32);
  const float rs = 1.0f / sum;

  // ---- stage v and p to wave-private LDS ----
#pragma unroll
  for (int c = 0; c < 4; ++c)
    *reinterpret_cast<short8*>(&vld[w][vt][vd0 + c * 8]) = vreg[c];
#pragma unroll
  for (int e = 0; e < 4; ++e)
    pld[w][((l >> 4) << 2) + e][l & 15] = p[e] * rs;
  asm volatile("s_waitcnt lgkmcnt(0)" ::: "memory");  // wave-private, no bar

  // ---- PV: lane owns h = l>>2, d-chunk = (l&3)*32 ----
  const int ph = l >> 2, pd0 = (l & 3) * 32;
  float o[32];
#pragma unroll
  for (int e = 0; e < 32; ++e) o[e] = 0.f;
  for (int t = 0; t < 16; ++t) {
    const float pv = pld[w][t][ph];
#pragma unroll
    for (int c = 0; c < 4; ++c) {
      const short8 vv =
          *reinterpret_cast<const short8*>(&vld[w][t][pd0 + c * 8]);
#pragma unroll
      for (int e2 = 0; e2 < 8; ++e2) o[c * 8 + e2] += pv * bf2f((u16)vv[e2]);
    }
  }

  // ---- store attn[token][h*128 + d] ----
  u16* dst = attn + (size_t)token * 2048 + ph * 128 + pd0;
#pragma unroll
  for (int c = 0; c < 4; ++c) {
    short8 ov;
#pragma unroll
    for (int e2 = 0; e2 < 8; ++e2) ov[e2] = (short)f2bf(o[c * 8 + e2]);
    *reinterpret_cast<short8*>(dst + c * 8) = ov;
  }
}

// ---------------------------------------------------------------------------
extern "C" void kernel_launch(void* const* d_in, const int* in_sizes, int n_in,
                              void* d_out, int out_size, void* d_ws,
                              size_t ws_size, hipStream_t stream) {
  (void)in_sizes;
  (void)n_in;
  (void)out_size;
  (void)ws_size;
  const float* x = (const float*)d_in[0];
  const float* Wq = (const float*)d_in[1];
  const float* Wk = (const float*)d_in[2];
  const float* Wv = (const float*)d_in[3];
  const float* Wo = (const float*)d_in[4];
  float* out = (float*)d_out;

  const int B = 4, S = 4096, D = 2048;
  const int M = B * S;  // 16384

  char* ws = (char*)d_ws;
  u16* xb = (u16*)ws;                          // M*D bf16; reused as attn
  u16* wqkv = (u16*)(ws + (size_t)M * D * 2);  // 3*D*D bf16
  u16* wo = (u16*)((char*)wqkv + (size_t)3 * D * D * 2);  // contiguous after
  u16* qkv = (u16*)((char*)wo + (size_t)D * D * 2);       // M*3D bf16

  // x -> bf16
  cvt_f32_to_bf16_v4<<<(M * D / 4 + 255) / 256, 256, 0, stream>>>(x, xb,
                                                                  M * D / 4);
  // all 4 weights -> bf16 in one launch (wqkv ++ wo are contiguous)
  cvt_w4<<<4 * (D * D / 4) / 256, 256, 0, stream>>>(Wq, Wk, Wv, Wo, wqkv);

  // qkv = x @ [Wq;Wk;Wv]^T   (M x 3D, bf16 out)
  gemm_bt<0><<<dim3(3 * D / 128, M / 128), 256, 0, stream>>>(xb, wqkv, qkv, M,
                                                             3 * D, D);
  // RoPE + per-token head attention -> attn (reuses xb); 4 tokens/block
  rope_attn2<<<M / 4, 256, 0, stream>>>(qkv, xb, S);
  // out = attn @ Wo^T (f32 out)
  gemm_bt<1><<<dim3(D / 128, M / 128), 256, 0, stream>>>(xb, wo, out, M, D, D);
}